// Round 2
// baseline (846.433 us; speedup 1.0000x reference)
//
#include <hip/hip_runtime.h>
#include <hip/hip_bf16.h>
#include <stdint.h>

// Problem constants
#define S_LEN 4096
#define B_DIM 8
#define E_DIM 1024
#define H_DIM 16
#define M_ROWS (S_LEN * B_DIM)   // 32768
#define N_QKV (3 * E_DIM)        // 3072
#define HB_DIM (H_DIM * B_DIM)   // 128

typedef float f32x4 __attribute__((ext_vector_type(4)));
typedef short bf16x8 __attribute__((ext_vector_type(8)));

#define MFMA16(a, b, c) __builtin_amdgcn_mfma_f32_16x16x32_bf16(a, b, c, 0, 0, 0)

__device__ __forceinline__ short f2bf(float f) {
  __hip_bfloat16 h = __float2bfloat16(f);
  short s;
  __builtin_memcpy(&s, &h, 2);
  return s;
}
__device__ __forceinline__ float bf2f(short b) {
  unsigned u = ((unsigned)(unsigned short)b) << 16;
  float f;
  __builtin_memcpy(&f, &u, 4);
  return f;
}
__device__ __forceinline__ void gl_lds16(const void* g, void* l) {
  __builtin_amdgcn_global_load_lds(
      (const __attribute__((address_space(1))) void*)g,
      (__attribute__((address_space(3))) void*)l, 16, 0, 0);
}

// ---------------------------------------------------------------------------
// K1: cast fp32 -> bf16 for x, w_qkv, w_out, w_f (one thread = 4 elements)
// ---------------------------------------------------------------------------
__global__ __launch_bounds__(256) void cast_all(
    const float* __restrict__ x, const float* __restrict__ wqkv,
    const float* __restrict__ wout, const float* __restrict__ wf,
    short* __restrict__ xb, short* __restrict__ wqb,
    short* __restrict__ wob, short* __restrict__ wfb) {
  const long n_x = (long)M_ROWS * E_DIM;          // 33554432
  const long n_wq = 3L * E_DIM * E_DIM;           // 3145728
  const long n_wo = (long)E_DIM * E_DIM;          // 1048576
  long idx = ((long)blockIdx.x * 256 + threadIdx.x) * 4;
  const float* src;
  short* dst;
  if (idx < n_x) {
    src = x + idx; dst = xb + idx;
  } else if ((idx -= n_x) < n_wq) {
    src = wqkv + idx; dst = wqb + idx;
  } else if ((idx -= n_wq) < n_wo) {
    src = wout + idx; dst = wob + idx;
  } else {
    idx -= n_wo;  // w_f: 4096 elements
    src = wf + idx; dst = wfb + idx;
  }
  float4 v = *(const float4*)src;
  short4 o;
  o.x = f2bf(v.x); o.y = f2bf(v.y); o.z = f2bf(v.z); o.w = f2bf(v.w);
  *(short4*)dst = o;
}

// ---------------------------------------------------------------------------
// K2/K6: C[m,n] = sum_k A[m,k]*B[n,k]; A: MxK bf16 row-major, B: NxK bf16
// row-major. 128x128 tile, BK=64, 256 threads (4 waves, each 64x64),
// global_load_lds width-16 staging with XOR-swizzled LDS layout:
//   position pc of row r holds global 16B-chunk pc ^ (r&7)  -> ds_read_b128
//   fragment loads hit all 8 bank-groups uniformly (8 lanes each = optimum).
// OUT_F32=1 adds bias and stores fp32.
// ---------------------------------------------------------------------------
template <int OUT_F32>
__global__ __launch_bounds__(256) void gemm_bt(
    const short* __restrict__ A, const short* __restrict__ Bm,
    void* __restrict__ Cout, const float* __restrict__ bias, int M, int N,
    int K) {
  __shared__ short As[128 * 64];
  __shared__ short Bs[128 * 64];
  const int t = threadIdx.x;
  const int w = t >> 6, l = t & 63;
  const int q = l >> 4, c = l & 15;
  const int bm = blockIdx.y * 128;
  const int bn = blockIdx.x * 128;

  // staging: LDS dest = w*4096 + j*1024 + l*16 -> row = w*32+j*8+(l>>3),
  // position (l&7). Global chunk loaded = (l&7) ^ (l>>3)  (the swizzle).
  const int row_a = w * 32 + (l >> 3);
  const int colb = ((l & 7) ^ (l >> 3)) * 16;
  const char* gA = (const char*)(A + (long)(bm + row_a) * K) + colb;
  const char* gB = (const char*)(Bm + (long)(bn + row_a) * K) + colb;
  char* lA = (char*)As + w * 4096 + l * 16;
  char* lB = (char*)Bs + w * 4096 + l * 16;
  const long strideAj = (long)8 * K * 2;  // 8 rows in bytes

  f32x4 acc[4][4];
#pragma unroll
  for (int i = 0; i < 4; i++)
#pragma unroll
    for (int j = 0; j < 4; j++) acc[i][j] = (f32x4){0.f, 0.f, 0.f, 0.f};

  const int mo = (w >> 1) * 64, no = (w & 1) * 64;

  for (int k0 = 0; k0 < K; k0 += 64) {
    __syncthreads();  // previous compute's ds_reads done before overwrite
#pragma unroll
    for (int j = 0; j < 4; j++) {
      gl_lds16(gA + (long)k0 * 2 + j * strideAj, lA + j * 1024);
      gl_lds16(gB + (long)k0 * 2 + j * strideAj, lB + j * 1024);
    }
    __syncthreads();  // drains vmcnt (global_load_lds) before use
#pragma unroll
    for (int kk = 0; kk < 2; kk++) {
      const int sw = ((kk * 4 + q) ^ (c & 7)) * 8;  // unswizzle (shorts)
      bf16x8 af[4], bfr[4];
#pragma unroll
      for (int mi = 0; mi < 4; mi++)
        af[mi] = *(const bf16x8*)(As + (mo + mi * 16 + c) * 64 + sw);
#pragma unroll
      for (int ni = 0; ni < 4; ni++)
        bfr[ni] = *(const bf16x8*)(Bs + (no + ni * 16 + c) * 64 + sw);
#pragma unroll
      for (int mi = 0; mi < 4; mi++)
#pragma unroll
        for (int ni = 0; ni < 4; ni++)
          acc[mi][ni] = MFMA16(af[mi], bfr[ni], acc[mi][ni]);
    }
  }

  // epilogue: C/D layout col = c, row = q*4 + r
  if (OUT_F32) {
    float* C = (float*)Cout;
#pragma unroll
    for (int ni = 0; ni < 4; ni++) {
      int n = bn + no + ni * 16 + c;
      float bo = bias[n];
#pragma unroll
      for (int mi = 0; mi < 4; mi++)
#pragma unroll
        for (int r = 0; r < 4; r++) {
          int m = bm + mo + mi * 16 + q * 4 + r;
          C[(long)m * N + n] = acc[mi][ni][r] + bo;
        }
    }
  } else {
    short* C = (short*)Cout;
#pragma unroll
    for (int ni = 0; ni < 4; ni++) {
      int n = bn + no + ni * 16 + c;
#pragma unroll
      for (int mi = 0; mi < 4; mi++)
#pragma unroll
        for (int r = 0; r < 4; r++) {
          int m = bm + mo + mi * 16 + q * 4 + r;
          C[(long)m * N + n] = f2bf(acc[mi][ni][r]);
        }
    }
  }
}

// ---------------------------------------------------------------------------
// K3: fused feature map + kv + ksum. Per block: (h, b, 256 s); wave owns 64 s.
//   Qp[h,b,s,p] = relu(q . w_f[p] + b_f[p])   -> global (s-major, for attn)
//   k'          = relu(k . w_f[p] + b_f[p])   -> registers (s-major C-frags)
//   ksumf[hb,p] += sum_s k'[s,p]              (shfl-reduce + global atomic)
//   kvf[hb, d*64+p] += sum_s v[s,d]*k'[s,p]   (per-wave LDS roundtrip ->
//       A/B-frag layout -> MFMA over 32-s chunks -> LDS-atomic block reduce
//       -> global fp32 atomics)
// LDS: 4 waves x (K' 64x48 + V 64x48 shorts) = 48 KiB + 16 KiB kvred = 64 KiB.
// stride 48 shorts = 96 B: 16B-aligned b128 reads, uniform bank spread.
// ---------------------------------------------------------------------------
__global__ __launch_bounds__(256) void feature_kv_kernel(
    const short* __restrict__ qkv, const short* __restrict__ wfb,
    const float* __restrict__ b_f, short* __restrict__ Qp,
    float* __restrict__ kvf, float* __restrict__ ksumf) {
  __shared__ short KVl[4][2][64 * 48];
  __shared__ float kvred[4096];

  const int bx = blockIdx.x;
  const int sblk = bx & 15, b = (bx >> 4) & 7, h = bx >> 7;
  const int t = threadIdx.x, w = t >> 6, l = t & 63;
  const int q = l >> 4, c = l & 15;
  const int s_base = sblk * 256 + w * 64;
  const int hb = h * 8 + b;

  for (int i = t; i < 4096; i += 256) kvred[i] = 0.f;

  // w_f fragments (rows = p), usable as A and B operand
  bf16x8 wf[4][2];
#pragma unroll
  for (int ti = 0; ti < 4; ti++)
#pragma unroll
    for (int kk = 0; kk < 2; kk++)
      wf[ti][kk] = *(const bf16x8*)(wfb + (ti * 16 + c) * 64 + kk * 32 + q * 8);

  float bfc[4];
#pragma unroll
  for (int ni = 0; ni < 4; ni++) bfc[ni] = b_f[ni * 16 + c];

  f32x4 acc[4][4];
  bf16x8 xf[4][2];

  // ---- Phase Q: Qp (s-major) ----
#pragma unroll
  for (int i = 0; i < 4; i++)
#pragma unroll
    for (int j = 0; j < 4; j++) acc[i][j] = (f32x4){0.f, 0.f, 0.f, 0.f};
#pragma unroll
  for (int mi = 0; mi < 4; mi++) {
    long ridx = (long)((s_base + mi * 16 + c) * 8 + b) * N_QKV;
#pragma unroll
    for (int kk = 0; kk < 2; kk++)
      xf[mi][kk] = *(const bf16x8*)(qkv + ridx + h * 64 + kk * 32 + q * 8);
  }
#pragma unroll
  for (int kk = 0; kk < 2; kk++)
#pragma unroll
    for (int mi = 0; mi < 4; mi++)
#pragma unroll
      for (int ni = 0; ni < 4; ni++)
        acc[mi][ni] = MFMA16(xf[mi][kk], wf[ni][kk], acc[mi][ni]);
#pragma unroll
  for (int mi = 0; mi < 4; mi++)
#pragma unroll
    for (int ni = 0; ni < 4; ni++)
#pragma unroll
      for (int r = 0; r < 4; r++) {
        int s = s_base + mi * 16 + q * 4 + r;
        float v = fmaxf(acc[mi][ni][r] + bfc[ni], 0.f);
        Qp[((long)hb * S_LEN + s) * 64 + ni * 16 + c] = f2bf(v);
      }

  // ---- Phase K: k' (s-major, stays in registers) ----
#pragma unroll
  for (int i = 0; i < 4; i++)
#pragma unroll
    for (int j = 0; j < 4; j++) acc[i][j] = (f32x4){0.f, 0.f, 0.f, 0.f};
#pragma unroll
  for (int mi = 0; mi < 4; mi++) {
    long ridx = (long)((s_base + mi * 16 + c) * 8 + b) * N_QKV;
#pragma unroll
    for (int kk = 0; kk < 2; kk++)
      xf[mi][kk] =
          *(const bf16x8*)(qkv + ridx + E_DIM + h * 64 + kk * 32 + q * 8);
  }
#pragma unroll
  for (int kk = 0; kk < 2; kk++)
#pragma unroll
    for (int mi = 0; mi < 4; mi++)
#pragma unroll
      for (int ni = 0; ni < 4; ni++)
        acc[mi][ni] = MFMA16(xf[mi][kk], wf[ni][kk], acc[mi][ni]);
  // bias + relu in place
#pragma unroll
  for (int mi = 0; mi < 4; mi++)
#pragma unroll
    for (int ni = 0; ni < 4; ni++)
#pragma unroll
      for (int r = 0; r < 4; r++)
        acc[mi][ni][r] = fmaxf(acc[mi][ni][r] + bfc[ni], 0.f);

  // ksum partial: lane sum over its 16 s, reduce across the 4 quads
#pragma unroll
  for (int ni = 0; ni < 4; ni++) {
    float s = 0.f;
#pragma unroll
    for (int mi = 0; mi < 4; mi++)
#pragma unroll
      for (int r = 0; r < 4; r++) s += acc[mi][ni][r];
    s += __shfl_xor(s, 16, 64);
    s += __shfl_xor(s, 32, 64);
    if (q == 0) atomicAdd(&ksumf[hb * 64 + ni * 16 + c], s);
  }

  // kv: two 32-s chunks through per-wave LDS
  short* kl = KVl[w][0];
  short* vl = KVl[w][1];
  f32x4 akv[4][4];
#pragma unroll
  for (int i = 0; i < 4; i++)
#pragma unroll
    for (int j = 0; j < 4; j++) akv[i][j] = (f32x4){0.f, 0.f, 0.f, 0.f};

  for (int ch = 0; ch < 2; ch++) {
    // scatter k' -> Kl[p][s_loc] (b64-packed along r)
#pragma unroll
    for (int mi2 = 0; mi2 < 2; mi2++) {
      int mi = ch * 2 + mi2;
#pragma unroll
      for (int ni = 0; ni < 4; ni++) {
        short4 pk;
        pk.x = f2bf(acc[mi][ni][0]);
        pk.y = f2bf(acc[mi][ni][1]);
        pk.z = f2bf(acc[mi][ni][2]);
        pk.w = f2bf(acc[mi][ni][3]);
        *(short4*)(kl + (ni * 16 + c) * 48 + mi2 * 16 + q * 4) = pk;
      }
    }
    // load v (s-major) and scatter transposed -> Vl[d][s_loc]
#pragma unroll
    for (int si2 = 0; si2 < 2; si2++) {
      int s = s_base + ch * 32 + si2 * 16 + c;
      const short* vsrc = qkv + ((long)s * 8 + b) * N_QKV + 2 * E_DIM + h * 64;
      int sl = si2 * 16 + c;
#pragma unroll
      for (int kk = 0; kk < 2; kk++) {
        bf16x8 vv = *(const bf16x8*)(vsrc + kk * 32 + q * 8);
#pragma unroll
        for (int j = 0; j < 8; j++) vl[(kk * 32 + q * 8 + j) * 48 + sl] = vv[j];
      }
    }
    // kv MFMA: A = V rows (d), B = K' rows (p), K = 32 (this chunk)
#pragma unroll
    for (int di = 0; di < 4; di++) {
      bf16x8 a = *(const bf16x8*)(vl + (di * 16 + c) * 48 + q * 8);
#pragma unroll
      for (int pi = 0; pi < 4; pi++) {
        bf16x8 bb = *(const bf16x8*)(kl + (pi * 16 + c) * 48 + q * 8);
        akv[di][pi] = MFMA16(a, bb, akv[di][pi]);
      }
    }
  }

  // block-level reduce in LDS, then one set of global atomics per block
  __syncthreads();  // kvred zero complete; all waves ready
#pragma unroll
  for (int di = 0; di < 4; di++)
#pragma unroll
    for (int pi = 0; pi < 4; pi++)
#pragma unroll
      for (int r = 0; r < 4; r++)
        atomicAdd(&kvred[(di * 16 + q * 4 + r) * 64 + pi * 16 + c],
                  akv[di][pi][r]);
  __syncthreads();
  float* dst = kvf + (long)hb * 4096;
  for (int i = t; i < 4096; i += 256) atomicAdd(dst + i, kvred[i]);
}

// K4: cast kvf/ksumf fp32 -> bf16
__global__ __launch_bounds__(256) void kv_cast(const float* __restrict__ kvf,
                                               const float* __restrict__ ksumf,
                                               short* __restrict__ kvb,
                                               short* __restrict__ ksumb) {
  int i = blockIdx.x * 256 + threadIdx.x;
  if (i < HB_DIM * 4096) {
    kvb[i] = f2bf(kvf[i]);
  } else {
    int j = i - HB_DIM * 4096;
    if (j < HB_DIM * 64) ksumb[j] = f2bf(ksumf[j]);
  }
}

// ---------------------------------------------------------------------------
// K5: num = Qp @ kvT^T (K=64), norm via masked-b_frag MFMA column, divide,
// write attn into (S,B,E) bf16 layout.
// ---------------------------------------------------------------------------
__global__ __launch_bounds__(256) void attn_kernel(
    const short* __restrict__ Qp, const short* __restrict__ kvb,
    const short* __restrict__ ksum, short* __restrict__ attn) {
  const int bx = blockIdx.x;
  const int sblk = bx & 15, b = (bx >> 4) & 7, h = bx >> 7;
  const int t = threadIdx.x, w = t >> 6, l = t & 63;
  const int q = l >> 4, c = l & 15;
  const int s_base = sblk * 256 + w * 64;
  const int hb = h * 8 + b;

  bf16x8 bkv[4][2];
#pragma unroll
  for (int ni = 0; ni < 4; ni++)
#pragma unroll
    for (int kk = 0; kk < 2; kk++)
      bkv[ni][kk] = *(const bf16x8*)(kvb + (long)hb * 4096 +
                                     (ni * 16 + c) * 64 + kk * 32 + q * 8);
  bf16x8 bn[2];
  const bf16x8 zfrag = {0, 0, 0, 0, 0, 0, 0, 0};
#pragma unroll
  for (int kk = 0; kk < 2; kk++) {
    bf16x8 v = *(const bf16x8*)(ksum + hb * 64 + kk * 32 + q * 8);
    bn[kk] = (c == 0) ? v : zfrag;
  }

  bf16x8 af[4][2];
#pragma unroll
  for (int mi = 0; mi < 4; mi++)
#pragma unroll
    for (int kk = 0; kk < 2; kk++)
      af[mi][kk] = *(const bf16x8*)(Qp + ((long)hb * S_LEN + s_base + mi * 16 + c) * 64 +
                                    kk * 32 + q * 8);

  f32x4 acc[4][4], accn[4];
#pragma unroll
  for (int i = 0; i < 4; i++) {
    accn[i] = (f32x4){0.f, 0.f, 0.f, 0.f};
#pragma unroll
    for (int j = 0; j < 4; j++) acc[i][j] = (f32x4){0.f, 0.f, 0.f, 0.f};
  }
#pragma unroll
  for (int kk = 0; kk < 2; kk++)
#pragma unroll
    for (int mi = 0; mi < 4; mi++) {
      accn[mi] = MFMA16(af[mi][kk], bn[kk], accn[mi]);
#pragma unroll
      for (int ni = 0; ni < 4; ni++)
        acc[mi][ni] = MFMA16(af[mi][kk], bkv[ni][kk], acc[mi][ni]);
    }

#pragma unroll
  for (int mi = 0; mi < 4; mi++)
#pragma unroll
    for (int r = 0; r < 4; r++) {
      float nv = __shfl(accn[mi][r], l & 48, 64);  // col-0 lane of this quad
      float inv = 1.f / (nv + 1e-8f);
      int s = s_base + mi * 16 + q * 4 + r;
#pragma unroll
      for (int ni = 0; ni < 4; ni++) {
        float v = acc[mi][ni][r] * inv;
        attn[((long)s * 8 + b) * E_DIM + h * 64 + ni * 16 + c] = f2bf(v);
      }
    }
}

// ---------------------------------------------------------------------------
// Launch
// ---------------------------------------------------------------------------
extern "C" void kernel_launch(void* const* d_in, const int* in_sizes, int n_in,
                              void* d_out, int out_size, void* d_ws,
                              size_t ws_size, hipStream_t stream) {
  const float* x = (const float*)d_in[0];
  const float* w_qkv = (const float*)d_in[1];
  const float* w_out = (const float*)d_in[2];
  const float* b_out = (const float*)d_in[3];
  const float* w_f = (const float*)d_in[4];
  const float* b_f = (const float*)d_in[5];

  char* ws = (char*)d_ws;
  // workspace layout (bytes); total ~331 MiB
  constexpr size_t off_xb = 0;                       // 64 MB (aliased by attn)
  constexpr size_t off_wqb = 67108864;               // 6 MB
  constexpr size_t off_wob = off_wqb + 6291456;      // 2 MB
  constexpr size_t off_wfb = off_wob + 2097152;      // 8 KB
  constexpr size_t off_qkv = off_wfb + 8192;         // 192 MB
  constexpr size_t off_Qp = off_qkv + 201326592;     // 64 MB
  constexpr size_t off_kvf = off_Qp + 67108864;      // 2 MB
  constexpr size_t off_ksumf = off_kvf + 2097152;    // 32 KB
  constexpr size_t off_kvb = off_ksumf + 32768;      // 1 MB
  constexpr size_t off_ksumb = off_kvb + 1048576;    // 16 KB

  short* xb = (short*)(ws + off_xb);
  short* wqb = (short*)(ws + off_wqb);
  short* wob = (short*)(ws + off_wob);
  short* wfb = (short*)(ws + off_wfb);
  short* qkv = (short*)(ws + off_qkv);
  short* Qp = (short*)(ws + off_Qp);
  float* kvf = (float*)(ws + off_kvf);
  float* ksumf = (float*)(ws + off_ksumf);
  short* kvb = (short*)(ws + off_kvb);
  short* ksumb = (short*)(ws + off_ksumb);
  short* attn = xb;  // alias: xb dead after QKV GEMM

  // zero fp32 accumulators (kvf + ksumf contiguous)
  hipMemsetAsync(kvf, 0, 2097152 + 32768, stream);

  // K1: casts (37752832 elements / 4 per thread)
  cast_all<<<36868, 256, 0, stream>>>(x, w_qkv, w_out, w_f, xb, wqb, wob, wfb);

  // K2: qkv = xb @ wqb^T  (M=32768, N=3072, K=1024)
  gemm_bt<0><<<dim3(N_QKV / 128, M_ROWS / 128), 256, 0, stream>>>(
      xb, wqb, qkv, nullptr, M_ROWS, N_QKV, E_DIM);

  // K3: fused feature maps + kv + ksum
  feature_kv_kernel<<<2048, 256, 0, stream>>>(qkv, wfb, b_f, Qp, kvf, ksumf);

  // K4: cast kv/ksum to bf16
  kv_cast<<<2080, 256, 0, stream>>>(kvf, ksumf, kvb, ksumb);

  // K5: attn = (Qp @ kv) / (Qp . ksum), into (S,B,E) bf16
  attn_kernel<<<2048, 256, 0, stream>>>(Qp, kvb, ksumb, attn);

  // K6: out = attn @ w_out^T + b_out  (fp32)
  gemm_bt<1><<<dim3(E_DIM / 128, M_ROWS / 128), 256, 0, stream>>>(
      attn, wob, (float*)d_out, b_out, M_ROWS, E_DIM, E_DIM);
}